// Round 4
// baseline (266.957 us; speedup 1.0000x reference)
//
#include <hip/hip_runtime.h>

typedef __attribute__((ext_vector_type(8))) short bf16x8;
typedef __attribute__((ext_vector_type(4))) float f32x4;
typedef __attribute__((ext_vector_type(16))) float f32x16;
typedef unsigned int u32;

#define S_LEN 2048
#define HIDDEN 2048
#define NH 16
#define NKV 2
#define DH 128
#define BATCH 2

__device__ __forceinline__ short f2bf(float f) {
  union { float f; u32 u; } x; x.f = f;
  u32 r = x.u + 0x7fffu + ((x.u >> 16) & 1u);
  return (short)(r >> 16);
}
__device__ __forceinline__ float bf2f(short s) {
  union { u32 u; float f; } x; x.u = ((u32)(unsigned short)s) << 16;
  return x.f;
}
__device__ __forceinline__ void load_lds_16(const void* g, void* l) {
  __builtin_amdgcn_global_load_lds(
      (const __attribute__((address_space(1))) u32*)g,
      (__attribute__((address_space(3))) u32*)l, 16, 0, 0);
}
__device__ __forceinline__ u32 cvt_pk_bf16(float lo, float hi) {
  u32 d;
  asm("v_cvt_pk_bf16_f32 %0, %1, %2" : "=v"(d) : "v"(lo), "v"(hi));
  return d;
}

// ---------------- f32 -> bf16 convert ----------------
__global__ void cvt_bf16_k(const float* __restrict__ in, short* __restrict__ out, int n4) {
  int i = blockIdx.x * 256 + threadIdx.x;
  if (i >= n4) return;
  const float4 v = ((const float4*)in)[i];
  short4 o;
  o.x = f2bf(v.x); o.y = f2bf(v.y); o.z = f2bf(v.z); o.w = f2bf(v.w);
  ((short4*)out)[i] = o;
}

__global__ void bias_concat_k(const float* __restrict__ qb, const float* __restrict__ kb,
                              const float* __restrict__ vb, float* __restrict__ out) {
  int i = blockIdx.x * 256 + threadIdx.x;
  if (i < 2048) out[i] = qb[i];
  else if (i < 2304) out[i] = kb[i - 2048];
  else if (i < 2560) out[i] = vb[i - 2304];
}

// ---------------- NT GEMM (unchanged) ----------------
template<int OUT_BF16, int BIAS>
__global__ __launch_bounds__(256, 2) void gemm_nt_k(
    const short* __restrict__ A, const short* __restrict__ Bw,
    const float* __restrict__ bias, void* __restrict__ Cout,
    int M, int N, int K) {
  __shared__ short As[128 * 32];
  __shared__ short Bs[128 * 32];
  const int tid = threadIdx.x;
  const int lane = tid & 63;
  const int w = tid >> 6;
  const int bn = blockIdx.x, bm = blockIdx.y;
  const int wm = (w >> 1) * 64, wn = (w & 1) * 64;
  const int l15 = lane & 15, l4 = lane >> 4;
  f32x4 acc[4][4] = {};

  const int sr = lane >> 2;
  const int sp = lane & 3;
  const int nk = K >> 5;
  for (int kt = 0; kt < nk; ++kt) {
    const int k0 = kt << 5;
    __syncthreads();
#pragma unroll
    for (int r = 0; r < 2; ++r) {
      const int kb = w + r * 4;
      const int row = kb * 16 + sr;
      const int gcol = (sp ^ ((row >> 1) & 3)) * 8;
      load_lds_16(A + (size_t)(bm * 128 + row) * K + k0 + gcol, &As[kb * 512]);
      load_lds_16(Bw + (size_t)(bn * 128 + row) * K + k0 + gcol, &Bs[kb * 512]);
    }
    __syncthreads();
    bf16x8 af[4], bfr[4];
#pragma unroll
    for (int i = 0; i < 4; ++i) {
      const int ra = wm + i * 16 + l15;
      af[i] = *(const bf16x8*)&As[ra * 32 + (l4 ^ ((ra >> 1) & 3)) * 8];
      const int rb = wn + i * 16 + l15;
      bfr[i] = *(const bf16x8*)&Bs[rb * 32 + (l4 ^ ((rb >> 1) & 3)) * 8];
    }
#pragma unroll
    for (int i = 0; i < 4; ++i)
#pragma unroll
      for (int j = 0; j < 4; ++j)
        acc[i][j] = __builtin_amdgcn_mfma_f32_16x16x32_bf16(af[i], bfr[j], acc[i][j], 0, 0, 0);
  }
#pragma unroll
  for (int j = 0; j < 4; ++j) {
    const int n = bn * 128 + wn + j * 16 + l15;
    float bv = 0.f;
    if (BIAS) bv = bias[n];
#pragma unroll
    for (int i = 0; i < 4; ++i) {
      const int mbase = bm * 128 + wm + i * 16 + l4 * 4;
#pragma unroll
      for (int r = 0; r < 4; ++r) {
        const float v = acc[i][j][r] + bv;
        if (OUT_BF16) ((short*)Cout)[(size_t)(mbase + r) * N + n] = f2bf(v);
        else          ((float*)Cout)[(size_t)(mbase + r) * N + n] = v;
      }
    }
  }
}

// ---------------- RoPE + repack Q,K ----------------
__global__ void rope_repack_k(const short* __restrict__ qkv,
                              const float* __restrict__ cosb,
                              const float* __restrict__ sinb,
                              short* __restrict__ Qo, short* __restrict__ Ko) {
  const int idx = blockIdx.x * 256 + threadIdx.x;
  const int d0 = idx & 63;
  const int rest = idx >> 6;
  const int head = rest % 18;
  const int bs = rest / 18;
  const int s = bs & (S_LEN - 1);
  const int b = bs >> 11;
  const short* row = qkv + (size_t)bs * 2560 + head * 128;
  const float x1 = bf2f(row[d0]);
  const float x2 = bf2f(row[d0 + 64]);
  const float c = cosb[s * 128 + d0];
  const float sn = sinb[s * 128 + d0];
  const float o1 = x1 * c - x2 * sn;
  const float o2 = x2 * c + x1 * sn;
  if (head < NH) {
    const float sc = 0.08838834764831845f * 1.4426950408889634f;  // D^-0.5 * log2(e)
    short* q = Qo + ((size_t)(b * NH + head) * S_LEN + s) * DH;
    q[d0] = f2bf(o1 * sc);
    q[d0 + 64] = f2bf(o2 * sc);
  } else {
    short* k = Ko + ((size_t)(b * NKV + (head - NH)) * S_LEN + s) * DH;
    k[d0] = f2bf(o1);
    k[d0 + 64] = f2bf(o2);
  }
}

// ---------------- V transpose ----------------
__global__ void vtrans_k(const short* __restrict__ qkv, short* __restrict__ VT) {
  __shared__ short t[64][65];
  const int s0 = blockIdx.x * 64;
  const int z = blockIdx.y;
  const int dt = z & 1, kvh = (z >> 1) & 1, b = z >> 2;
  const int d0 = dt * 64;
  const int c = threadIdx.x & 63, rr = threadIdx.x >> 6;
#pragma unroll
  for (int i = 0; i < 16; ++i) {
    const int sl = rr + i * 4;
    t[sl][c] = qkv[(size_t)(b * S_LEN + s0 + sl) * 2560 + 2304 + kvh * 128 + d0 + c];
  }
  __syncthreads();
#pragma unroll
  for (int i = 0; i < 16; ++i) {
    const int dl = rr + i * 4;
    VT[((size_t)(b * NKV + kvh) * DH + d0 + dl) * S_LEN + s0 + c] = t[c][dl];
  }
}

// ---------------- causal GQA flash attention ----------------
// R4: V direct global->reg (L2/L3-resident; drops half of LDS reads + half of
// staging writes). K stays in LDS dbuf. Per iteration:
//   issue V_t (16 dwordx4) ; issue K_{t+1} stage (4 load_lds)
//   vmcnt(20) -> K_t landed ; barrier ; QK^T ; barrier (Ks free)
//   softmax (V_t landing under it) ; repack ; PV (compiler waits vf exactly)
__global__ __launch_bounds__(256, 2) void attn_k(
    const short* __restrict__ Qb, const short* __restrict__ Kb,
    const short* __restrict__ VTb, short* __restrict__ Ob) {
  __shared__ short Ks[2][64 * 128];
  const int tid = threadIdx.x, lane = tid & 63, w = tid >> 6;
  const int n = blockIdx.x;
  const int half = n >> 8, r8 = n & 255;
  const int bh = r8 >> 3, p = r8 & 7;
  const int x = half ? (15 - p) : p;      // q-tile 0..15
  const int b = bh >> 4, h = bh & 15;
  const int kvh = h >> 3;
  const int l31 = lane & 31, hi = lane >> 5;
  const int qw = x * 128 + w * 32;        // wave q base
  const int q = qw + l31;                 // this lane's q row

  bf16x8 qf[8];
  {
    const short* qrow = Qb + ((size_t)(b * NH + h) * S_LEN + q) * DH;
#pragma unroll
    for (int s = 0; s < 8; ++s)
      qf[s] = *(const bf16x8*)(qrow + s * 16 + hi * 8);
  }
  f32x16 o[4] = {};   // O^T tiles: o[dt][r] = O[q][d=(r&3)+8*(r>>2)+4hi+32dt]
  float m_r = -1e30f, l_r = 0.f;

  const short* Kbase = Kb + (size_t)(b * NKV + kvh) * S_LEN * DH;
  const short* Vbase = VTb + (size_t)(b * NKV + kvh) * DH * S_LEN;

  auto stageK = [&](int bi, int t) {
    const int kv0 = t << 6;
#pragma unroll
    for (int r = 0; r < 4; ++r) {
      const int kb = r * 4 + w;
      const int krow = kb * 4 + (lane >> 4);
      const int gs = ((lane & 15) ^ (krow & 7)) * 8;
      load_lds_16(Kbase + (size_t)(kv0 + krow) * DH + gs, &Ks[bi][kb * 512]);
    }
  };

  const int ntile = 2 * x + 2;
  stageK(0, 0);
  int cur = 0;
  for (int t = 0; t < ntile; ++t) {
    const int kv0 = t << 6;
    const bool active = (kv0 <= qw + 31);
    // ---- V tile t: direct global->reg (linear layout, no swizzle) ----
    bf16x8 vf[4][4];
#pragma unroll
    for (int s = 0; s < 4; ++s)
#pragma unroll
      for (int dt = 0; dt < 4; ++dt)
        vf[s][dt] = *(const bf16x8*)(Vbase + (size_t)(dt * 32 + l31) * S_LEN +
                                     kv0 + s * 16 + hi * 8);
    // ---- K tile t+1 staging ----
    if (t + 1 < ntile) {
      stageK(cur ^ 1, t + 1);
      asm volatile("s_waitcnt vmcnt(20)" ::: "memory");  // K_t landed (V_t+K_{t+1} in flight)
    } else {
      asm volatile("s_waitcnt vmcnt(16)" ::: "memory");  // K_t landed (V_t in flight)
    }
    __builtin_amdgcn_s_barrier();
    f32x16 sc0 = {}, sc1 = {};
    if (active) {
      const short* Ksb = Ks[cur];
      __builtin_amdgcn_s_setprio(1);
#pragma unroll
      for (int s = 0; s < 8; ++s) {
        const int sl = ((2 * s + hi) ^ (l31 & 7)) * 8;
        const bf16x8 kf0 = *(const bf16x8*)&Ksb[l31 * 128 + sl];
        const bf16x8 kf1 = *(const bf16x8*)&Ksb[(l31 + 32) * 128 + sl];
        sc0 = __builtin_amdgcn_mfma_f32_32x32x16_bf16(kf0, qf[s], sc0, 0, 0, 0);
        sc1 = __builtin_amdgcn_mfma_f32_32x32x16_bf16(kf1, qf[s], sc1, 0, 0, 0);
      }
      __builtin_amdgcn_s_setprio(0);
    }
    asm volatile("" ::: "memory");
    __builtin_amdgcn_s_barrier();   // all QK reads of Ks[cur] done -> restage safe next iter
    if (active) {
      // ---- causal mask ----
      if (kv0 + 63 > qw) {
#pragma unroll
        for (int r = 0; r < 16; ++r) {
          const int kva = kv0 + (r & 3) + 8 * (r >> 2) + 4 * hi;
          if (kva > q) sc0[r] = -1e30f;
          if (kva + 32 > q) sc1[r] = -1e30f;
        }
      }
      // ---- in-register online softmax ----
      float pm = -1e30f;
#pragma unroll
      for (int r = 0; r < 16; ++r)
        pm = fmaxf(pm, fmaxf(sc0[r], sc1[r]));
      pm = fmaxf(pm, __shfl_xor(pm, 32));
      if (__any(pm > m_r + 8.f)) {   // T13 defer-rescale
        const float nm = fmaxf(m_r, pm);
        const float fr = exp2f(m_r - nm);
        l_r *= fr;
#pragma unroll
        for (int dt = 0; dt < 4; ++dt)
#pragma unroll
          for (int r = 0; r < 16; ++r)
            o[dt][r] *= fr;
        m_r = nm;
      }
      float rs = 0.f;
#pragma unroll
      for (int r = 0; r < 16; ++r) {
        sc0[r] = exp2f(sc0[r] - m_r); rs += sc0[r];
        sc1[r] = exp2f(sc1[r] - m_r); rs += sc1[r];
      }
      rs += __shfl_xor(rs, 32);
      l_r += rs;
      // ---- P -> PV fragments: 16 cvt_pk + 8 permlane32_swap ----
      u32 e0 = cvt_pk_bf16(sc0[0], sc0[1]),  e1 = cvt_pk_bf16(sc0[2], sc0[3]);
      u32 e2 = cvt_pk_bf16(sc0[4], sc0[5]),  e3 = cvt_pk_bf16(sc0[6], sc0[7]);
      u32 e4 = cvt_pk_bf16(sc0[8], sc0[9]),  e5 = cvt_pk_bf16(sc0[10], sc0[11]);
      u32 e6 = cvt_pk_bf16(sc0[12], sc0[13]), e7 = cvt_pk_bf16(sc0[14], sc0[15]);
      u32 f0 = cvt_pk_bf16(sc1[0], sc1[1]),  f1 = cvt_pk_bf16(sc1[2], sc1[3]);
      u32 f2 = cvt_pk_bf16(sc1[4], sc1[5]),  f3 = cvt_pk_bf16(sc1[6], sc1[7]);
      u32 f4 = cvt_pk_bf16(sc1[8], sc1[9]),  f5 = cvt_pk_bf16(sc1[10], sc1[11]);
      u32 f6 = cvt_pk_bf16(sc1[12], sc1[13]), f7 = cvt_pk_bf16(sc1[14], sc1[15]);
      asm("v_permlane32_swap_b32 %0, %1" : "+v"(e0), "+v"(e2));
      asm("v_permlane32_swap_b32 %0, %1" : "+v"(e1), "+v"(e3));
      asm("v_permlane32_swap_b32 %0, %1" : "+v"(e4), "+v"(e6));
      asm("v_permlane32_swap_b32 %0, %1" : "+v"(e5), "+v"(e7));
      asm("v_permlane32_swap_b32 %0, %1" : "+v"(f0), "+v"(f2));
      asm("v_permlane32_swap_b32 %0, %1" : "+v"(f1), "+v"(f3));
      asm("v_permlane32_swap_b32 %0, %1" : "+v"(f4), "+v"(f6));
      asm("v_permlane32_swap_b32 %0, %1" : "+v"(f5), "+v"(f7));
      union { u32 u[4]; bf16x8 v; } pk0, pk1, pk2, pk3;
      pk0.u[0] = e0; pk0.u[1] = e1; pk0.u[2] = e2; pk0.u[3] = e3;  // kv 0..15
      pk1.u[0] = e4; pk1.u[1] = e5; pk1.u[2] = e6; pk1.u[3] = e7;  // kv 16..31
      pk2.u[0] = f0; pk2.u[1] = f1; pk2.u[2] = f2; pk2.u[3] = f3;  // kv 32..47
      pk3.u[0] = f4; pk3.u[1] = f5; pk3.u[2] = f6; pk3.u[3] = f7;  // kv 48..63
      bf16x8 pa[4] = {pk0.v, pk1.v, pk2.v, pk3.v};
      // ---- PV: O^T[d][q] += V^T[d][kv] * P^T[kv][q] (vf from registers) ----
      __builtin_amdgcn_s_setprio(1);
#pragma unroll
      for (int s = 0; s < 4; ++s) {
#pragma unroll
        for (int dt = 0; dt < 4; ++dt)
          o[dt] = __builtin_amdgcn_mfma_f32_32x32x16_bf16(vf[s][dt], pa[s], o[dt], 0, 0, 0);
      }
      __builtin_amdgcn_s_setprio(0);
    }
    cur ^= 1;
  }

  // ---- epilogue ----
  const float invl = 1.f / l_r;
  short* orow = Ob + (size_t)(b * S_LEN + q) * (NH * DH) + h * DH;
#pragma unroll
  for (int dt = 0; dt < 4; ++dt)
#pragma unroll
    for (int g = 0; g < 4; ++g) {
      short4 st;
      st.x = f2bf(o[dt][4 * g + 0] * invl);
      st.y = f2bf(o[dt][4 * g + 1] * invl);
      st.z = f2bf(o[dt][4 * g + 2] * invl);
      st.w = f2bf(o[dt][4 * g + 3] * invl);
      *(short4*)(orow + dt * 32 + 8 * g + 4 * hi) = st;
    }
}

// ---------------- launch ----------------
extern "C" void kernel_launch(void* const* d_in, const int* in_sizes, int n_in,
                              void* d_out, int out_size, void* d_ws, size_t ws_size,
                              hipStream_t stream) {
  const float* hid  = (const float*)d_in[0];
  const float* cosb = (const float*)d_in[1];
  const float* sinb = (const float*)d_in[2];
  const float* q_w  = (const float*)d_in[3];
  const float* q_b  = (const float*)d_in[4];
  const float* k_w  = (const float*)d_in[5];
  const float* k_b  = (const float*)d_in[6];
  const float* v_w  = (const float*)d_in[7];
  const float* v_b  = (const float*)d_in[8];
  const float* o_w  = (const float*)d_in[9];
  (void)in_sizes; (void)n_in; (void)out_size; (void)ws_size;

  char* ws = (char*)d_ws;
  short* x_bf   = (short*)(ws + 0);
  short* w_bf   = (short*)(ws + 16777216);
  short* ow_bf  = (short*)(ws + 27262976);
  float* biasc  = (float*)(ws + 35651584);
  short* qkv_bf = (short*)(ws + 35667968);
  short* q_bf   = (short*)(ws + 56639488);
  short* k_bf   = (short*)(ws + 73416704);
  short* vT_bf  = (short*)(ws + 75513856);
  short* att_o  = (short*)(ws + 77611008);

  hipLaunchKernelGGL(cvt_bf16_k, dim3(8192), dim3(256), 0, stream, hid, x_bf, 2097152);
  hipLaunchKernelGGL(cvt_bf16_k, dim3(4096), dim3(256), 0, stream, q_w, w_bf, 1048576);
  hipLaunchKernelGGL(cvt_bf16_k, dim3(512),  dim3(256), 0, stream, k_w, w_bf + 2048 * 2048, 131072);
  hipLaunchKernelGGL(cvt_bf16_k, dim3(512),  dim3(256), 0, stream, v_w, w_bf + 2304 * 2048, 131072);
  hipLaunchKernelGGL(cvt_bf16_k, dim3(4096), dim3(256), 0, stream, o_w, ow_bf, 1048576);
  hipLaunchKernelGGL(bias_concat_k, dim3(10), dim3(256), 0, stream, q_b, k_b, v_b, biasc);
  hipLaunchKernelGGL((gemm_nt_k<1, 1>), dim3(20, 32), dim3(256), 0, stream,
                     x_bf, w_bf, biasc, qkv_bf, 4096, 2560, 2048);
  hipLaunchKernelGGL(rope_repack_k, dim3(18432), dim3(256), 0, stream,
                     qkv_bf, cosb, sinb, q_bf, k_bf);
  hipLaunchKernelGGL(vtrans_k, dim3(32, 8), dim3(256), 0, stream, qkv_bf, vT_bf);
  hipLaunchKernelGGL(attn_k, dim3(512), dim3(256), 0, stream, q_bf, k_bf, vT_bf, att_o);
  hipLaunchKernelGGL((gemm_nt_k<0, 0>), dim3(16, 32), dim3(256), 0, stream,
                     att_o, ow_bf, (const float*)nullptr, d_out, 4096, 2048, 2048);
}

// Round 5
// 248.586 us; speedup vs baseline: 1.0739x; 1.0739x over previous
//
#include <hip/hip_runtime.h>

typedef __attribute__((ext_vector_type(8))) short bf16x8;
typedef __attribute__((ext_vector_type(4))) float f32x4;
typedef __attribute__((ext_vector_type(16))) float f32x16;
typedef unsigned int u32;

#define S_LEN 2048
#define HIDDEN 2048
#define NH 16
#define NKV 2
#define DH 128
#define BATCH 2

__device__ __forceinline__ short f2bf(float f) {
  union { float f; u32 u; } x; x.f = f;
  u32 r = x.u + 0x7fffu + ((x.u >> 16) & 1u);
  return (short)(r >> 16);
}
__device__ __forceinline__ float bf2f(short s) {
  union { u32 u; float f; } x; x.u = ((u32)(unsigned short)s) << 16;
  return x.f;
}
__device__ __forceinline__ void load_lds_16(const void* g, void* l) {
  __builtin_amdgcn_global_load_lds(
      (const __attribute__((address_space(1))) u32*)g,
      (__attribute__((address_space(3))) u32*)l, 16, 0, 0);
}
__device__ __forceinline__ u32 cvt_pk_bf16(float lo, float hi) {
  u32 d;
  asm("v_cvt_pk_bf16_f32 %0, %1, %2" : "=v"(d) : "v"(lo), "v"(hi));
  return d;
}

// ---------------- f32 -> bf16 convert ----------------
__global__ void cvt_bf16_k(const float* __restrict__ in, short* __restrict__ out, int n4) {
  int i = blockIdx.x * 256 + threadIdx.x;
  if (i >= n4) return;
  const float4 v = ((const float4*)in)[i];
  short4 o;
  o.x = f2bf(v.x); o.y = f2bf(v.y); o.z = f2bf(v.z); o.w = f2bf(v.w);
  ((short4*)out)[i] = o;
}

__global__ void bias_concat_k(const float* __restrict__ qb, const float* __restrict__ kb,
                              const float* __restrict__ vb, float* __restrict__ out) {
  int i = blockIdx.x * 256 + threadIdx.x;
  if (i < 2048) out[i] = qb[i];
  else if (i < 2304) out[i] = kb[i - 2048];
  else if (i < 2560) out[i] = vb[i - 2304];
}

// ---------------- NT GEMM (unchanged) ----------------
template<int OUT_BF16, int BIAS>
__global__ __launch_bounds__(256, 2) void gemm_nt_k(
    const short* __restrict__ A, const short* __restrict__ Bw,
    const float* __restrict__ bias, void* __restrict__ Cout,
    int M, int N, int K) {
  __shared__ short As[128 * 32];
  __shared__ short Bs[128 * 32];
  const int tid = threadIdx.x;
  const int lane = tid & 63;
  const int w = tid >> 6;
  const int bn = blockIdx.x, bm = blockIdx.y;
  const int wm = (w >> 1) * 64, wn = (w & 1) * 64;
  const int l15 = lane & 15, l4 = lane >> 4;
  f32x4 acc[4][4] = {};

  const int sr = lane >> 2;
  const int sp = lane & 3;
  const int nk = K >> 5;
  for (int kt = 0; kt < nk; ++kt) {
    const int k0 = kt << 5;
    __syncthreads();
#pragma unroll
    for (int r = 0; r < 2; ++r) {
      const int kb = w + r * 4;
      const int row = kb * 16 + sr;
      const int gcol = (sp ^ ((row >> 1) & 3)) * 8;
      load_lds_16(A + (size_t)(bm * 128 + row) * K + k0 + gcol, &As[kb * 512]);
      load_lds_16(Bw + (size_t)(bn * 128 + row) * K + k0 + gcol, &Bs[kb * 512]);
    }
    __syncthreads();
    bf16x8 af[4], bfr[4];
#pragma unroll
    for (int i = 0; i < 4; ++i) {
      const int ra = wm + i * 16 + l15;
      af[i] = *(const bf16x8*)&As[ra * 32 + (l4 ^ ((ra >> 1) & 3)) * 8];
      const int rb = wn + i * 16 + l15;
      bfr[i] = *(const bf16x8*)&Bs[rb * 32 + (l4 ^ ((rb >> 1) & 3)) * 8];
    }
#pragma unroll
    for (int i = 0; i < 4; ++i)
#pragma unroll
      for (int j = 0; j < 4; ++j)
        acc[i][j] = __builtin_amdgcn_mfma_f32_16x16x32_bf16(af[i], bfr[j], acc[i][j], 0, 0, 0);
  }
#pragma unroll
  for (int j = 0; j < 4; ++j) {
    const int n = bn * 128 + wn + j * 16 + l15;
    float bv = 0.f;
    if (BIAS) bv = bias[n];
#pragma unroll
    for (int i = 0; i < 4; ++i) {
      const int mbase = bm * 128 + wm + i * 16 + l4 * 4;
#pragma unroll
      for (int r = 0; r < 4; ++r) {
        const float v = acc[i][j][r] + bv;
        if (OUT_BF16) ((short*)Cout)[(size_t)(mbase + r) * N + n] = f2bf(v);
        else          ((float*)Cout)[(size_t)(mbase + r) * N + n] = v;
      }
    }
  }
}

// ---------------- RoPE + repack Q,K ----------------
__global__ void rope_repack_k(const short* __restrict__ qkv,
                              const float* __restrict__ cosb,
                              const float* __restrict__ sinb,
                              short* __restrict__ Qo, short* __restrict__ Ko) {
  const int idx = blockIdx.x * 256 + threadIdx.x;
  const int d0 = idx & 63;
  const int rest = idx >> 6;
  const int head = rest % 18;
  const int bs = rest / 18;
  const int s = bs & (S_LEN - 1);
  const int b = bs >> 11;
  const short* row = qkv + (size_t)bs * 2560 + head * 128;
  const float x1 = bf2f(row[d0]);
  const float x2 = bf2f(row[d0 + 64]);
  const float c = cosb[s * 128 + d0];
  const float sn = sinb[s * 128 + d0];
  const float o1 = x1 * c - x2 * sn;
  const float o2 = x2 * c + x1 * sn;
  if (head < NH) {
    const float sc = 0.08838834764831845f * 1.4426950408889634f;  // D^-0.5 * log2(e)
    short* q = Qo + ((size_t)(b * NH + head) * S_LEN + s) * DH;
    q[d0] = f2bf(o1 * sc);
    q[d0 + 64] = f2bf(o2 * sc);
  } else {
    short* k = Ko + ((size_t)(b * NKV + (head - NH)) * S_LEN + s) * DH;
    k[d0] = f2bf(o1);
    k[d0 + 64] = f2bf(o2);
  }
}

// ---------------- V transpose ----------------
__global__ void vtrans_k(const short* __restrict__ qkv, short* __restrict__ VT) {
  __shared__ short t[64][65];
  const int s0 = blockIdx.x * 64;
  const int z = blockIdx.y;
  const int dt = z & 1, kvh = (z >> 1) & 1, b = z >> 2;
  const int d0 = dt * 64;
  const int c = threadIdx.x & 63, rr = threadIdx.x >> 6;
#pragma unroll
  for (int i = 0; i < 16; ++i) {
    const int sl = rr + i * 4;
    t[sl][c] = qkv[(size_t)(b * S_LEN + s0 + sl) * 2560 + 2304 + kvh * 128 + d0 + c];
  }
  __syncthreads();
#pragma unroll
  for (int i = 0; i < 16; ++i) {
    const int dl = rr + i * 4;
    VT[((size_t)(b * NKV + kvh) * DH + d0 + dl) * S_LEN + s0 + c] = t[c][dl];
  }
}

// ---------------- causal GQA flash attention ----------------
// R5: R3's proven inner loop (K+V LDS dbuf, swapped-QK^T, in-register softmax,
// vmcnt(8), 2 barriers), wrapped in TWO SEQUENTIAL q-tile streams per block:
// stream 0 = q-tile a (2a+2 kv-tiles), stream 1 = q-tile 15-a (32-2a kv-tiles).
// Every block does exactly 34 tile-iterations -> uniform duration, 2 blocks/CU
// pacing end-to-end (R3's half-map left CUs at 1 block after shorts finished).
__global__ __launch_bounds__(256, 2) void attn_k(
    const short* __restrict__ Qb, const short* __restrict__ Kb,
    const short* __restrict__ VTb, short* __restrict__ Ob) {
  __shared__ short Ks[2][64 * 128];
  __shared__ short Vs[2][128 * 64];
  const int tid = threadIdx.x, lane = tid & 63, w = tid >> 6;
  const int bid = blockIdx.x;             // 0..511
  const int a = bid >> 5;                 // 0..15
  const int bh = bid & 31;
  const int b = bh >> 4, h = bh & 15;
  const int kvh = h >> 3;
  const int l31 = lane & 31, hi = lane >> 5;

  const short* Kbase = Kb + (size_t)(b * NKV + kvh) * S_LEN * DH;
  const short* Vbase = VTb + (size_t)(b * NKV + kvh) * DH * S_LEN;

  auto stage = [&](int bi, int t) {
    const int kv0 = t << 6;
#pragma unroll
    for (int r = 0; r < 4; ++r) {
      const int kb = r * 4 + w;
      const int krow = kb * 4 + (lane >> 4);
      const int gs = ((lane & 15) ^ (krow & 7)) * 8;
      load_lds_16(Kbase + (size_t)(kv0 + krow) * DH + gs, &Ks[bi][kb * 512]);
    }
#pragma unroll
    for (int r = 0; r < 4; ++r) {
      const int kb = r * 4 + w;
      const int vrow = kb * 8 + (lane >> 3);
      const int gs = ((lane & 7) ^ (vrow & 7)) * 8;
      load_lds_16(Vbase + (size_t)vrow * S_LEN + kv0 + gs, &Vs[bi][kb * 512]);
    }
  };

  for (int si = 0; si < 2; ++si) {
    const int x = si ? (15 - a) : a;      // q-tile 0..15
    const int qw = x * 128 + w * 32;      // wave q base
    const int q = qw + l31;               // this lane's q row

    bf16x8 qf[8];
    {
      const short* qrow = Qb + ((size_t)(b * NH + h) * S_LEN + q) * DH;
#pragma unroll
      for (int s = 0; s < 8; ++s)
        qf[s] = *(const bf16x8*)(qrow + s * 16 + hi * 8);
    }
    f32x16 o[4] = {};   // O^T tiles: o[dt][r] = O[q][d=(r&3)+8*(r>>2)+4hi+32dt]
    float m_r = -1e30f, l_r = 0.f;

    const int ntile = 2 * x + 2;
    stage(0, 0);
    int cur = 0;
    for (int t = 0; t < ntile; ++t) {
      const int kv0 = t << 6;
      if (t + 1 < ntile) {
        stage(cur ^ 1, t + 1);
        asm volatile("s_waitcnt vmcnt(8)" ::: "memory");
      } else {
        asm volatile("s_waitcnt vmcnt(0)" ::: "memory");
      }
      __builtin_amdgcn_s_barrier();
      asm volatile("" ::: "memory");
      if (kv0 <= qw + 31) {
        const short* Ksb = Ks[cur];
        const short* Vsb = Vs[cur];
        // ---- QK^T (swapped): sc0 = kv 0..31, sc1 = kv 32..63 ----
        f32x16 sc0 = {}, sc1 = {};
        __builtin_amdgcn_s_setprio(1);
#pragma unroll
        for (int s = 0; s < 8; ++s) {
          const int sl = ((2 * s + hi) ^ (l31 & 7)) * 8;
          const bf16x8 kf0 = *(const bf16x8*)&Ksb[l31 * 128 + sl];
          const bf16x8 kf1 = *(const bf16x8*)&Ksb[(l31 + 32) * 128 + sl];
          sc0 = __builtin_amdgcn_mfma_f32_32x32x16_bf16(kf0, qf[s], sc0, 0, 0, 0);
          sc1 = __builtin_amdgcn_mfma_f32_32x32x16_bf16(kf1, qf[s], sc1, 0, 0, 0);
        }
        __builtin_amdgcn_s_setprio(0);
        // ---- causal mask (partial tiles only; wave-uniform branch) ----
        if (kv0 + 63 > qw) {
#pragma unroll
          for (int r = 0; r < 16; ++r) {
            const int kva = kv0 + (r & 3) + 8 * (r >> 2) + 4 * hi;
            if (kva > q) sc0[r] = -1e30f;
            if (kva + 32 > q) sc1[r] = -1e30f;
          }
        }
        // ---- in-register online softmax ----
        float pm = -1e30f;
#pragma unroll
        for (int r = 0; r < 16; ++r)
          pm = fmaxf(pm, fmaxf(sc0[r], sc1[r]));
        pm = fmaxf(pm, __shfl_xor(pm, 32));
        if (__any(pm > m_r + 8.f)) {   // T13 defer-rescale, THR=8 (exp2 domain)
          const float nm = fmaxf(m_r, pm);
          const float fr = exp2f(m_r - nm);
          l_r *= fr;
#pragma unroll
          for (int dt = 0; dt < 4; ++dt)
#pragma unroll
            for (int r = 0; r < 16; ++r)
              o[dt][r] *= fr;
          m_r = nm;
        }
        float rs = 0.f;
#pragma unroll
        for (int r = 0; r < 16; ++r) {
          sc0[r] = exp2f(sc0[r] - m_r); rs += sc0[r];
          sc1[r] = exp2f(sc1[r] - m_r); rs += sc1[r];
        }
        rs += __shfl_xor(rs, 32);
        l_r += rs;
        // ---- P -> PV fragments: 16 cvt_pk + 8 permlane32_swap ----
        u32 e0 = cvt_pk_bf16(sc0[0], sc0[1]),  e1 = cvt_pk_bf16(sc0[2], sc0[3]);
        u32 e2 = cvt_pk_bf16(sc0[4], sc0[5]),  e3 = cvt_pk_bf16(sc0[6], sc0[7]);
        u32 e4 = cvt_pk_bf16(sc0[8], sc0[9]),  e5 = cvt_pk_bf16(sc0[10], sc0[11]);
        u32 e6 = cvt_pk_bf16(sc0[12], sc0[13]), e7 = cvt_pk_bf16(sc0[14], sc0[15]);
        u32 f0 = cvt_pk_bf16(sc1[0], sc1[1]),  f1 = cvt_pk_bf16(sc1[2], sc1[3]);
        u32 f2 = cvt_pk_bf16(sc1[4], sc1[5]),  f3 = cvt_pk_bf16(sc1[6], sc1[7]);
        u32 f4 = cvt_pk_bf16(sc1[8], sc1[9]),  f5 = cvt_pk_bf16(sc1[10], sc1[11]);
        u32 f6 = cvt_pk_bf16(sc1[12], sc1[13]), f7 = cvt_pk_bf16(sc1[14], sc1[15]);
        asm("v_permlane32_swap_b32 %0, %1" : "+v"(e0), "+v"(e2));
        asm("v_permlane32_swap_b32 %0, %1" : "+v"(e1), "+v"(e3));
        asm("v_permlane32_swap_b32 %0, %1" : "+v"(e4), "+v"(e6));
        asm("v_permlane32_swap_b32 %0, %1" : "+v"(e5), "+v"(e7));
        asm("v_permlane32_swap_b32 %0, %1" : "+v"(f0), "+v"(f2));
        asm("v_permlane32_swap_b32 %0, %1" : "+v"(f1), "+v"(f3));
        asm("v_permlane32_swap_b32 %0, %1" : "+v"(f4), "+v"(f6));
        asm("v_permlane32_swap_b32 %0, %1" : "+v"(f5), "+v"(f7));
        union { u32 u[4]; bf16x8 v; } pk0, pk1, pk2, pk3;
        pk0.u[0] = e0; pk0.u[1] = e1; pk0.u[2] = e2; pk0.u[3] = e3;  // kv 0..15
        pk1.u[0] = e4; pk1.u[1] = e5; pk1.u[2] = e6; pk1.u[3] = e7;  // kv 16..31
        pk2.u[0] = f0; pk2.u[1] = f1; pk2.u[2] = f2; pk2.u[3] = f3;  // kv 32..47
        pk3.u[0] = f4; pk3.u[1] = f5; pk3.u[2] = f6; pk3.u[3] = f7;  // kv 48..63
        bf16x8 pa[4] = {pk0.v, pk1.v, pk2.v, pk3.v};
        // ---- PV: O^T[d][q] += V^T[d][kv] * P^T[kv][q] ----
        __builtin_amdgcn_s_setprio(1);
#pragma unroll
        for (int s = 0; s < 4; ++s) {
#pragma unroll
          for (int dt = 0; dt < 4; ++dt) {
            const int row = dt * 32 + l31;
            const int sl = ((2 * s + hi) ^ (l31 & 7)) * 8;
            const bf16x8 vf = *(const bf16x8*)&Vsb[row * 64 + sl];
            o[dt] = __builtin_amdgcn_mfma_f32_32x32x16_bf16(vf, pa[s], o[dt], 0, 0, 0);
          }
        }
        __builtin_amdgcn_s_setprio(0);
      }
      asm volatile("" ::: "memory");
      __builtin_amdgcn_s_barrier();
      cur ^= 1;
    }

    // ---- epilogue: normalize + pack short4 stores ----
    const float invl = 1.f / l_r;
    short* orow = Ob + (size_t)(b * S_LEN + q) * (NH * DH) + h * DH;
#pragma unroll
    for (int dt = 0; dt < 4; ++dt)
#pragma unroll
      for (int g = 0; g < 4; ++g) {
        short4 st;
        st.x = f2bf(o[dt][4 * g + 0] * invl);
        st.y = f2bf(o[dt][4 * g + 1] * invl);
        st.z = f2bf(o[dt][4 * g + 2] * invl);
        st.w = f2bf(o[dt][4 * g + 3] * invl);
        *(short4*)(orow + dt * 32 + 8 * g + 4 * hi) = st;
      }
  }
}

// ---------------- launch ----------------
extern "C" void kernel_launch(void* const* d_in, const int* in_sizes, int n_in,
                              void* d_out, int out_size, void* d_ws, size_t ws_size,
                              hipStream_t stream) {
  const float* hid  = (const float*)d_in[0];
  const float* cosb = (const float*)d_in[1];
  const float* sinb = (const float*)d_in[2];
  const float* q_w  = (const float*)d_in[3];
  const float* q_b  = (const float*)d_in[4];
  const float* k_w  = (const float*)d_in[5];
  const float* k_b  = (const float*)d_in[6];
  const float* v_w  = (const float*)d_in[7];
  const float* v_b  = (const float*)d_in[8];
  const float* o_w  = (const float*)d_in[9];
  (void)in_sizes; (void)n_in; (void)out_size; (void)ws_size;

  char* ws = (char*)d_ws;
  short* x_bf   = (short*)(ws + 0);
  short* w_bf   = (short*)(ws + 16777216);
  short* ow_bf  = (short*)(ws + 27262976);
  float* biasc  = (float*)(ws + 35651584);
  short* qkv_bf = (short*)(ws + 35667968);
  short* q_bf   = (short*)(ws + 56639488);
  short* k_bf   = (short*)(ws + 73416704);
  short* vT_bf  = (short*)(ws + 75513856);
  short* att_o  = (short*)(ws + 77611008);

  hipLaunchKernelGGL(cvt_bf16_k, dim3(8192), dim3(256), 0, stream, hid, x_bf, 2097152);
  hipLaunchKernelGGL(cvt_bf16_k, dim3(4096), dim3(256), 0, stream, q_w, w_bf, 1048576);
  hipLaunchKernelGGL(cvt_bf16_k, dim3(512),  dim3(256), 0, stream, k_w, w_bf + 2048 * 2048, 131072);
  hipLaunchKernelGGL(cvt_bf16_k, dim3(512),  dim3(256), 0, stream, v_w, w_bf + 2304 * 2048, 131072);
  hipLaunchKernelGGL(cvt_bf16_k, dim3(4096), dim3(256), 0, stream, o_w, ow_bf, 1048576);
  hipLaunchKernelGGL(bias_concat_k, dim3(10), dim3(256), 0, stream, q_b, k_b, v_b, biasc);
  hipLaunchKernelGGL((gemm_nt_k<1, 1>), dim3(20, 32), dim3(256), 0, stream,
                     x_bf, w_bf, biasc, qkv_bf, 4096, 2560, 2048);
  hipLaunchKernelGGL(rope_repack_k, dim3(18432), dim3(256), 0, stream,
                     qkv_bf, cosb, sinb, q_bf, k_bf);
  hipLaunchKernelGGL(vtrans_k, dim3(32, 8), dim3(256), 0, stream, qkv_bf, vT_bf);
  hipLaunchKernelGGL(attn_k, dim3(512), dim3(256), 0, stream, q_bf, k_bf, vT_bf, att_o);
  hipLaunchKernelGGL((gemm_nt_k<0, 0>), dim3(16, 32), dim3(256), 0, stream,
                     att_o, ow_bf, (const float*)nullptr, d_out, 4096, 2048, 2048);
}

// Round 6
// 212.689 us; speedup vs baseline: 1.2552x; 1.1688x over previous
//
#include <hip/hip_runtime.h>

typedef __attribute__((ext_vector_type(8))) short bf16x8;
typedef __attribute__((ext_vector_type(4))) float f32x4;
typedef __attribute__((ext_vector_type(16))) float f32x16;
typedef unsigned int u32;

#define S_LEN 2048
#define HIDDEN 2048
#define NH 16
#define NKV 2
#define DH 128
#define BATCH 2

__device__ __forceinline__ short f2bf(float f) {
  union { float f; u32 u; } x; x.f = f;
  u32 r = x.u + 0x7fffu + ((x.u >> 16) & 1u);
  return (short)(r >> 16);
}
__device__ __forceinline__ float bf2f(short s) {
  union { u32 u; float f; } x; x.u = ((u32)(unsigned short)s) << 16;
  return x.f;
}
__device__ __forceinline__ void load_lds_16(const void* g, void* l) {
  __builtin_amdgcn_global_load_lds(
      (const __attribute__((address_space(1))) u32*)g,
      (__attribute__((address_space(3))) u32*)l, 16, 0, 0);
}
__device__ __forceinline__ u32 cvt_pk_bf16(float lo, float hi) {
  u32 d;
  asm("v_cvt_pk_bf16_f32 %0, %1, %2" : "=v"(d) : "v"(lo), "v"(hi));
  return d;
}

// ---------------- f32 -> bf16 convert ----------------
__global__ void cvt_bf16_k(const float* __restrict__ in, short* __restrict__ out, int n4) {
  int i = blockIdx.x * 256 + threadIdx.x;
  if (i >= n4) return;
  const float4 v = ((const float4*)in)[i];
  short4 o;
  o.x = f2bf(v.x); o.y = f2bf(v.y); o.z = f2bf(v.z); o.w = f2bf(v.w);
  ((short4*)out)[i] = o;
}

__global__ void bias_concat_k(const float* __restrict__ qb, const float* __restrict__ kb,
                              const float* __restrict__ vb, float* __restrict__ out) {
  int i = blockIdx.x * 256 + threadIdx.x;
  if (i < 2048) out[i] = qb[i];
  else if (i < 2304) out[i] = kb[i - 2048];
  else if (i < 2560) out[i] = vb[i - 2304];
}

// ---------------- NT GEMM: C[m,n] = sum_k A[m,k]*B[n,k] (+bias) ----------------
// launch_bounds (256,3): m97-structure runs 3 blocks/CU at <=170 VGPR.
template<int OUT_BF16, int BIAS>
__global__ __launch_bounds__(256, 3) void gemm_nt_k(
    const short* __restrict__ A, const short* __restrict__ Bw,
    const float* __restrict__ bias, void* __restrict__ Cout,
    int M, int N, int K) {
  __shared__ short As[128 * 32];
  __shared__ short Bs[128 * 32];
  const int tid = threadIdx.x;
  const int lane = tid & 63;
  const int w = tid >> 6;
  const int bn = blockIdx.x, bm = blockIdx.y;
  const int wm = (w >> 1) * 64, wn = (w & 1) * 64;
  const int l15 = lane & 15, l4 = lane >> 4;
  f32x4 acc[4][4] = {};

  const int sr = lane >> 2;
  const int sp = lane & 3;
  const int nk = K >> 5;
  for (int kt = 0; kt < nk; ++kt) {
    const int k0 = kt << 5;
    __syncthreads();
#pragma unroll
    for (int r = 0; r < 2; ++r) {
      const int kb = w + r * 4;
      const int row = kb * 16 + sr;
      const int gcol = (sp ^ ((row >> 1) & 3)) * 8;
      load_lds_16(A + (size_t)(bm * 128 + row) * K + k0 + gcol, &As[kb * 512]);
      load_lds_16(Bw + (size_t)(bn * 128 + row) * K + k0 + gcol, &Bs[kb * 512]);
    }
    __syncthreads();
    bf16x8 af[4], bfr[4];
#pragma unroll
    for (int i = 0; i < 4; ++i) {
      const int ra = wm + i * 16 + l15;
      af[i] = *(const bf16x8*)&As[ra * 32 + (l4 ^ ((ra >> 1) & 3)) * 8];
      const int rb = wn + i * 16 + l15;
      bfr[i] = *(const bf16x8*)&Bs[rb * 32 + (l4 ^ ((rb >> 1) & 3)) * 8];
    }
#pragma unroll
    for (int i = 0; i < 4; ++i)
#pragma unroll
      for (int j = 0; j < 4; ++j)
        acc[i][j] = __builtin_amdgcn_mfma_f32_16x16x32_bf16(af[i], bfr[j], acc[i][j], 0, 0, 0);
  }
#pragma unroll
  for (int j = 0; j < 4; ++j) {
    const int n = bn * 128 + wn + j * 16 + l15;
    float bv = 0.f;
    if (BIAS) bv = bias[n];
#pragma unroll
    for (int i = 0; i < 4; ++i) {
      const int mbase = bm * 128 + wm + i * 16 + l4 * 4;
#pragma unroll
      for (int r = 0; r < 4; ++r) {
        const float v = acc[i][j][r] + bv;
        if (OUT_BF16) ((short*)Cout)[(size_t)(mbase + r) * N + n] = f2bf(v);
        else          ((float*)Cout)[(size_t)(mbase + r) * N + n] = v;
      }
    }
  }
}

// ---------------- RoPE + repack Q,K ----------------
__global__ void rope_repack_k(const short* __restrict__ qkv,
                              const float* __restrict__ cosb,
                              const float* __restrict__ sinb,
                              short* __restrict__ Qo, short* __restrict__ Ko) {
  const int idx = blockIdx.x * 256 + threadIdx.x;
  const int d0 = idx & 63;
  const int rest = idx >> 6;
  const int head = rest % 18;
  const int bs = rest / 18;
  const int s = bs & (S_LEN - 1);
  const int b = bs >> 11;
  const short* row = qkv + (size_t)bs * 2560 + head * 128;
  const float x1 = bf2f(row[d0]);
  const float x2 = bf2f(row[d0 + 64]);
  const float c = cosb[s * 128 + d0];
  const float sn = sinb[s * 128 + d0];
  const float o1 = x1 * c - x2 * sn;
  const float o2 = x2 * c + x1 * sn;
  if (head < NH) {
    const float sc = 0.08838834764831845f * 1.4426950408889634f;  // D^-0.5 * log2(e)
    short* q = Qo + ((size_t)(b * NH + head) * S_LEN + s) * DH;
    q[d0] = f2bf(o1 * sc);
    q[d0 + 64] = f2bf(o2 * sc);
  } else {
    short* k = Ko + ((size_t)(b * NKV + (head - NH)) * S_LEN + s) * DH;
    k[d0] = f2bf(o1);
    k[d0 + 64] = f2bf(o2);
  }
}

// ---------------- V transpose ----------------
__global__ void vtrans_k(const short* __restrict__ qkv, short* __restrict__ VT) {
  __shared__ short t[64][65];
  const int s0 = blockIdx.x * 64;
  const int z = blockIdx.y;
  const int dt = z & 1, kvh = (z >> 1) & 1, b = z >> 2;
  const int d0 = dt * 64;
  const int c = threadIdx.x & 63, rr = threadIdx.x >> 6;
#pragma unroll
  for (int i = 0; i < 16; ++i) {
    const int sl = rr + i * 4;
    t[sl][c] = qkv[(size_t)(b * S_LEN + s0 + sl) * 2560 + 2304 + kvh * 128 + d0 + c];
  }
  __syncthreads();
#pragma unroll
  for (int i = 0; i < 16; ++i) {
    const int dl = rr + i * 4;
    VT[((size_t)(b * NKV + kvh) * DH + d0 + dl) * S_LEN + s0 + c] = t[c][dl];
  }
}

// ---------------- causal GQA flash attention, kv-parity split-k ----------------
// 512 blocks = (a 0..7, bh 0..31, parity s 0..1). Block processes parity-s kv
// tiles of q-tile a (a+1 iters) then q-tile 15-a (16-a iters) = 17 iterations,
// identical for every block -> uniform 2-blocks/CU pacing end to end.
// Outputs UNNORMALIZED partials (O, m, l in exp2 domain); combine_k merges the
// two parities. Fully-masked rows keep m=-1e30 -> weight 2^(m-m*)=0 in combine.
__global__ __launch_bounds__(256, 2) void attn_k(
    const short* __restrict__ Qb, const short* __restrict__ Kb,
    const short* __restrict__ VTb, short* __restrict__ Opart,
    float2* __restrict__ ML) {
  __shared__ short Ks[2][64 * 128];
  __shared__ short Vs[2][128 * 64];
  const int tid = threadIdx.x, lane = tid & 63, w = tid >> 6;
  const int bid = blockIdx.x;             // 0..511
  const int s = bid & 1;                  // kv parity
  const int bh = (bid >> 1) & 31;
  const int a = bid >> 6;                 // 0..7
  const int b = bh >> 4, h = bh & 15;
  const int kvh = h >> 3;
  const int l31 = lane & 31, hi = lane >> 5;

  const short* Kbase = Kb + (size_t)(b * NKV + kvh) * S_LEN * DH;
  const short* Vbase = VTb + (size_t)(b * NKV + kvh) * DH * S_LEN;

  auto stage = [&](int bi, int tile) {
    const int kv0 = tile << 6;
#pragma unroll
    for (int r = 0; r < 4; ++r) {
      const int kb = r * 4 + w;
      const int krow = kb * 4 + (lane >> 4);
      const int gs = ((lane & 15) ^ (krow & 7)) * 8;
      load_lds_16(Kbase + (size_t)(kv0 + krow) * DH + gs, &Ks[bi][kb * 512]);
    }
#pragma unroll
    for (int r = 0; r < 4; ++r) {
      const int kb = r * 4 + w;
      const int vrow = kb * 8 + (lane >> 3);
      const int gs = ((lane & 7) ^ (vrow & 7)) * 8;
      load_lds_16(Vbase + (size_t)vrow * S_LEN + kv0 + gs, &Vs[bi][kb * 512]);
    }
  };

  for (int si = 0; si < 2; ++si) {
    const int x = si ? (15 - a) : a;      // q-tile 0..15
    const int cnt = si ? (16 - a) : (a + 1);  // parity tile count
    const int qw = x * 128 + w * 32;      // wave q base
    const int q = qw + l31;               // this lane's q row

    bf16x8 qf[8];
    {
      const short* qrow = Qb + ((size_t)(b * NH + h) * S_LEN + q) * DH;
#pragma unroll
      for (int ss = 0; ss < 8; ++ss)
        qf[ss] = *(const bf16x8*)(qrow + ss * 16 + hi * 8);
    }
    f32x16 o[4] = {};   // O^T tiles: o[dt][r] = O[q][d=(r&3)+8*(r>>2)+4hi+32dt]
    float m_r = -1e30f, l_r = 0.f;

    stage(0, s);
    int cur = 0;
    for (int j = 0; j < cnt; ++j) {
      const int kv0 = (s + 2 * j) << 6;
      if (j + 1 < cnt) {
        stage(cur ^ 1, s + 2 * (j + 1));
        asm volatile("s_waitcnt vmcnt(8)" ::: "memory");
      } else {
        asm volatile("s_waitcnt vmcnt(0)" ::: "memory");
      }
      __builtin_amdgcn_s_barrier();
      asm volatile("" ::: "memory");
      if (kv0 <= qw + 31) {
        const short* Ksb = Ks[cur];
        const short* Vsb = Vs[cur];
        // ---- QK^T (swapped): sc0 = kv 0..31, sc1 = kv 32..63 ----
        f32x16 sc0 = {}, sc1 = {};
        __builtin_amdgcn_s_setprio(1);
#pragma unroll
        for (int ss = 0; ss < 8; ++ss) {
          const int sl = ((2 * ss + hi) ^ (l31 & 7)) * 8;
          const bf16x8 kf0 = *(const bf16x8*)&Ksb[l31 * 128 + sl];
          const bf16x8 kf1 = *(const bf16x8*)&Ksb[(l31 + 32) * 128 + sl];
          sc0 = __builtin_amdgcn_mfma_f32_32x32x16_bf16(kf0, qf[ss], sc0, 0, 0, 0);
          sc1 = __builtin_amdgcn_mfma_f32_32x32x16_bf16(kf1, qf[ss], sc1, 0, 0, 0);
        }
        __builtin_amdgcn_s_setprio(0);
        // ---- causal mask (partial tiles only) ----
        if (kv0 + 63 > qw) {
#pragma unroll
          for (int r = 0; r < 16; ++r) {
            const int kva = kv0 + (r & 3) + 8 * (r >> 2) + 4 * hi;
            if (kva > q) sc0[r] = -1e30f;
            if (kva + 32 > q) sc1[r] = -1e30f;
          }
        }
        // ---- in-register online softmax ----
        float pm = -1e30f;
#pragma unroll
        for (int r = 0; r < 16; ++r)
          pm = fmaxf(pm, fmaxf(sc0[r], sc1[r]));
        pm = fmaxf(pm, __shfl_xor(pm, 32));
        if (__any(pm > m_r + 8.f)) {   // T13 defer-rescale
          const float nm = fmaxf(m_r, pm);
          const float fr = exp2f(m_r - nm);
          l_r *= fr;
#pragma unroll
          for (int dt = 0; dt < 4; ++dt)
#pragma unroll
            for (int r = 0; r < 16; ++r)
              o[dt][r] *= fr;
          m_r = nm;
        }
        float rs = 0.f;
#pragma unroll
        for (int r = 0; r < 16; ++r) {
          sc0[r] = exp2f(sc0[r] - m_r); rs += sc0[r];
          sc1[r] = exp2f(sc1[r] - m_r); rs += sc1[r];
        }
        rs += __shfl_xor(rs, 32);
        l_r += rs;
        // ---- P -> PV fragments: 16 cvt_pk + 8 permlane32_swap ----
        u32 e0 = cvt_pk_bf16(sc0[0], sc0[1]),  e1 = cvt_pk_bf16(sc0[2], sc0[3]);
        u32 e2 = cvt_pk_bf16(sc0[4], sc0[5]),  e3 = cvt_pk_bf16(sc0[6], sc0[7]);
        u32 e4 = cvt_pk_bf16(sc0[8], sc0[9]),  e5 = cvt_pk_bf16(sc0[10], sc0[11]);
        u32 e6 = cvt_pk_bf16(sc0[12], sc0[13]), e7 = cvt_pk_bf16(sc0[14], sc0[15]);
        u32 f0 = cvt_pk_bf16(sc1[0], sc1[1]),  f1 = cvt_pk_bf16(sc1[2], sc1[3]);
        u32 f2 = cvt_pk_bf16(sc1[4], sc1[5]),  f3 = cvt_pk_bf16(sc1[6], sc1[7]);
        u32 f4 = cvt_pk_bf16(sc1[8], sc1[9]),  f5 = cvt_pk_bf16(sc1[10], sc1[11]);
        u32 f6 = cvt_pk_bf16(sc1[12], sc1[13]), f7 = cvt_pk_bf16(sc1[14], sc1[15]);
        asm("v_permlane32_swap_b32 %0, %1" : "+v"(e0), "+v"(e2));
        asm("v_permlane32_swap_b32 %0, %1" : "+v"(e1), "+v"(e3));
        asm("v_permlane32_swap_b32 %0, %1" : "+v"(e4), "+v"(e6));
        asm("v_permlane32_swap_b32 %0, %1" : "+v"(e5), "+v"(e7));
        asm("v_permlane32_swap_b32 %0, %1" : "+v"(f0), "+v"(f2));
        asm("v_permlane32_swap_b32 %0, %1" : "+v"(f1), "+v"(f3));
        asm("v_permlane32_swap_b32 %0, %1" : "+v"(f4), "+v"(f6));
        asm("v_permlane32_swap_b32 %0, %1" : "+v"(f5), "+v"(f7));
        union { u32 u[4]; bf16x8 v; } pk0, pk1, pk2, pk3;
        pk0.u[0] = e0; pk0.u[1] = e1; pk0.u[2] = e2; pk0.u[3] = e3;  // kv 0..15
        pk1.u[0] = e4; pk1.u[1] = e5; pk1.u[2] = e6; pk1.u[3] = e7;  // kv 16..31
        pk2.u[0] = f0; pk2.u[1] = f1; pk2.u[2] = f2; pk2.u[3] = f3;  // kv 32..47
        pk3.u[0] = f4; pk3.u[1] = f5; pk3.u[2] = f6; pk3.u[3] = f7;  // kv 48..63
        bf16x8 pa[4] = {pk0.v, pk1.v, pk2.v, pk3.v};
        // ---- PV: O^T[d][q] += V^T[d][kv] * P^T[kv][q] ----
        __builtin_amdgcn_s_setprio(1);
#pragma unroll
        for (int ss = 0; ss < 4; ++ss) {
#pragma unroll
          for (int dt = 0; dt < 4; ++dt) {
            const int row = dt * 32 + l31;
            const int sl = ((2 * ss + hi) ^ (l31 & 7)) * 8;
            const bf16x8 vf = *(const bf16x8*)&Vsb[row * 64 + sl];
            o[dt] = __builtin_amdgcn_mfma_f32_32x32x16_bf16(vf, pa[ss], o[dt], 0, 0, 0);
          }
        }
        __builtin_amdgcn_s_setprio(0);
      }
      asm volatile("" ::: "memory");
      __builtin_amdgcn_s_barrier();
      cur ^= 1;
    }

    // ---- epilogue: store UNNORMALIZED partial + (m,l) ----
    const int T = ((bh * 16 + x) << 1) | s;
    const int ql = w * 32 + l31;
    short* orow = Opart + (size_t)T * 16384 + ql * 128;
#pragma unroll
    for (int dt = 0; dt < 4; ++dt)
#pragma unroll
      for (int g = 0; g < 4; ++g) {
        short4 st;
        st.x = f2bf(o[dt][4 * g + 0]);
        st.y = f2bf(o[dt][4 * g + 1]);
        st.z = f2bf(o[dt][4 * g + 2]);
        st.w = f2bf(o[dt][4 * g + 3]);
        *(short4*)(orow + dt * 32 + 8 * g + 4 * hi) = st;
      }
    if (hi == 0) ML[T * 128 + ql] = make_float2(m_r, l_r);
  }
}

// ---------------- combine the two kv-parity partials ----------------
__global__ void combine_k(const short* __restrict__ Opart,
                          const float2* __restrict__ ML,
                          short* __restrict__ att_o) {
  const int t = blockIdx.x * 256 + threadIdx.x;   // 2^20 threads
  const int d8 = t & 15;
  const int h  = (t >> 4) & 15;
  const int q  = (t >> 8) & 2047;
  const int b  = t >> 19;
  const int bh = b * 16 + h;
  const int x = q >> 7, ql = q & 127;
  const int T0 = (bh * 16 + x) << 1;
  const float2 a0 = ML[T0 * 128 + ql];
  const float2 a1 = ML[(T0 + 1) * 128 + ql];
  const float ms = fmaxf(a0.x, a1.x);
  const float w0 = exp2f(a0.x - ms), w1 = exp2f(a1.x - ms);
  const float inv = 1.f / (a0.y * w0 + a1.y * w1);
  const bf16x8 o0 = *(const bf16x8*)(Opart + (size_t)T0 * 16384 + ql * 128 + d8 * 8);
  const bf16x8 o1 = *(const bf16x8*)(Opart + (size_t)(T0 + 1) * 16384 + ql * 128 + d8 * 8);
  bf16x8 res;
#pragma unroll
  for (int i = 0; i < 8; ++i)
    res[i] = f2bf((bf2f(o0[i]) * w0 + bf2f(o1[i]) * w1) * inv);
  *(bf16x8*)(att_o + (size_t)(b * S_LEN + q) * (NH * DH) + h * DH + d8 * 8) = res;
}

// ---------------- launch ----------------
extern "C" void kernel_launch(void* const* d_in, const int* in_sizes, int n_in,
                              void* d_out, int out_size, void* d_ws, size_t ws_size,
                              hipStream_t stream) {
  const float* hid  = (const float*)d_in[0];
  const float* cosb = (const float*)d_in[1];
  const float* sinb = (const float*)d_in[2];
  const float* q_w  = (const float*)d_in[3];
  const float* q_b  = (const float*)d_in[4];
  const float* k_w  = (const float*)d_in[5];
  const float* k_b  = (const float*)d_in[6];
  const float* v_w  = (const float*)d_in[7];
  const float* v_b  = (const float*)d_in[8];
  const float* o_w  = (const float*)d_in[9];
  (void)in_sizes; (void)n_in; (void)out_size; (void)ws_size;

  char* ws = (char*)d_ws;
  // Region reuse across pipeline phases (no total growth vs R5):
  short*  x_bf   = (short*)(ws + 0);           // [4096][2048] bf16 (phase 1)
  short*  w_bf   = (short*)(ws + 16777216);    // [2560][2048] bf16 (phase 1)
  short*  Opart  = (short*)(ws + 0);           // [1024][128][128] bf16 (attn phase; overlays x_bf/w_bf)
  float2* MLbuf  = (float2*)(ws + 33554432);   // [1024][128] float2 (attn phase)
  float*  biasc  = (float*)(ws + 35651584);    // [2560] f32
  short*  qkv_bf = (short*)(ws + 35667968);    // [4096][2560] bf16 (phase 1-2)
  short*  ow_bf  = (short*)(ws + 35667968);    // [2048][2048] bf16 (phase 3+; overlays dead qkv)
  short*  q_bf   = (short*)(ws + 56639488);    // [B][H][S][D] bf16
  short*  k_bf   = (short*)(ws + 73416704);    // [B][KV][S][D] bf16
  short*  vT_bf  = (short*)(ws + 75513856);    // [B][KV][D][S] bf16
  short*  att_o  = (short*)(ws + 77611008);    // [4096][2048] bf16

  hipLaunchKernelGGL(cvt_bf16_k, dim3(8192), dim3(256), 0, stream, hid, x_bf, 2097152);
  hipLaunchKernelGGL(cvt_bf16_k, dim3(4096), dim3(256), 0, stream, q_w, w_bf, 1048576);
  hipLaunchKernelGGL(cvt_bf16_k, dim3(512),  dim3(256), 0, stream, k_w, w_bf + 2048 * 2048, 131072);
  hipLaunchKernelGGL(cvt_bf16_k, dim3(512),  dim3(256), 0, stream, v_w, w_bf + 2304 * 2048, 131072);
  hipLaunchKernelGGL(bias_concat_k, dim3(10), dim3(256), 0, stream, q_b, k_b, v_b, biasc);
  hipLaunchKernelGGL((gemm_nt_k<1, 1>), dim3(20, 32), dim3(256), 0, stream,
                     x_bf, w_bf, biasc, qkv_bf, 4096, 2560, 2048);
  hipLaunchKernelGGL(rope_repack_k, dim3(18432), dim3(256), 0, stream,
                     qkv_bf, cosb, sinb, q_bf, k_bf);
  hipLaunchKernelGGL(vtrans_k, dim3(32, 8), dim3(256), 0, stream, qkv_bf, vT_bf);
  // o_w convert AFTER vtrans: ow_bf overlays the now-dead qkv region.
  hipLaunchKernelGGL(cvt_bf16_k, dim3(4096), dim3(256), 0, stream, o_w, ow_bf, 1048576);
  hipLaunchKernelGGL(attn_k, dim3(512), dim3(256), 0, stream, q_bf, k_bf, vT_bf, Opart, MLbuf);
  hipLaunchKernelGGL(combine_k, dim3(4096), dim3(256), 0, stream, Opart, MLbuf, att_o);
  hipLaunchKernelGGL((gemm_nt_k<0, 0>), dim3(16, 32), dim3(256), 0, stream,
                     att_o, ow_bf, (const float*)nullptr, d_out, 4096, 2048, 2048);
}